// Round 1
// 624.968 us; speedup vs baseline: 1.1963x; 1.1963x over previous
//
#include <hip/hip_runtime.h>
#include <hip/hip_bf16.h>

// Performer / FAVOR+ noncausal attention. ALL inputs + output FLOAT32.
// Intermediates bf16/f32. MFMA (16x16x32 bf16) for GEMMs + fused num/den.
// This revision: kvs aggregation converted from scalar-VALU (151.7us,
// latency-bound) to MFMA via standalone swizzled transposes KP->KPt, V->Vt.
#define B_   4
#define L_   4096
#define HID_ 1024
#define H_   16
#define DH_  64
#define M_   128
#define BL_  (B_*L_)        // 16384
#define NROW (BL_*H_)       // 262144

using short8 = __attribute__((ext_vector_type(8))) short;
using f32x4  = __attribute__((ext_vector_type(4))) float;

__device__ __forceinline__ float b2f(ushort s) {
    return __builtin_bit_cast(float, (unsigned int)s << 16);
}
__device__ __forceinline__ ushort f2b(float f) {  // RNE
    unsigned int u = __builtin_bit_cast(unsigned int, f);
    u += 0x7fffu + ((u >> 16) & 1u);
    return (ushort)(u >> 16);
}

// async global->LDS, 16B per lane; LDS dest = wave-uniform base + lane*16
__device__ __forceinline__ void gld16(void* lds, const void* g) {
    __builtin_amdgcn_global_load_lds(
        (const __attribute__((address_space(1))) unsigned int*)g,
        (__attribute__((address_space(3))) unsigned int*)lds, 16, 0, 0);
}

// ---------------------------------------------------------------------------
// Generalized 128x128-tile MFMA K-loop. A[row][k] stride sA, BT[col][k] stride
// sB (both k-contiguous, 16B-aligned). LDS As/Bs: [kg(4)][r(128)][8] (8KB ea).
// 256 thr / 4 waves; wave w: rows (w>>1)*64.., cols (w&1)*64..; acc[4][4].
// ---------------------------------------------------------------------------
__device__ __forceinline__ void mfma_gemm_g(
    const ushort* __restrict__ A, const ushort* __restrict__ BT,
    int sA, int sB, int K, ushort* As, ushort* Bs, f32x4 acc[4][4])
{
    const int t = threadIdx.x, w = t >> 6, lane = t & 63;
    const int wm = w >> 1, wn = w & 1, kg = lane >> 4, lr = lane & 15;
    const ushort* a0 = A  + (size_t)lane * sA + w * 8;
    const ushort* a1 = A  + (size_t)(64 + lane) * sA + w * 8;
    const ushort* b0 = BT + (size_t)lane * sB + w * 8;
    const ushort* b1 = BT + (size_t)(64 + lane) * sB + w * 8;
    ushort* lA0 = As + (size_t)(w * 128) * 8;
    ushort* lA1 = As + (size_t)(w * 128 + 64) * 8;
    ushort* lB0 = Bs + (size_t)(w * 128) * 8;
    ushort* lB1 = Bs + (size_t)(w * 128 + 64) * 8;

    for (int k0 = 0; k0 < K; k0 += 32) {
        gld16(lA0, a0 + k0); gld16(lA1, a1 + k0);
        gld16(lB0, b0 + k0); gld16(lB1, b1 + k0);
        __syncthreads();
        short8 av[4], bv[4];
        #pragma unroll
        for (int i = 0; i < 4; ++i)
            av[i] = *(const short8*)(As + ((size_t)kg*128 + wm*64 + i*16 + lr) * 8);
        #pragma unroll
        for (int i = 0; i < 4; ++i)
            bv[i] = *(const short8*)(Bs + ((size_t)kg*128 + wn*64 + i*16 + lr) * 8);
        #pragma unroll
        for (int mt = 0; mt < 4; ++mt)
            #pragma unroll
            for (int nt = 0; nt < 4; ++nt)
                acc[mt][nt] = __builtin_amdgcn_mfma_f32_16x16x32_bf16(
                    av[mt], bv[nt], acc[mt][nt], 0, 0, 0);
        __syncthreads();
    }
}

// ---------------------------------------------------------------------------
// Fused QK projection + phi (all-MFMA).
// grid (HID/128=8, BL/128=128); block covers heads h0=2*bx, h0+1.
// ---------------------------------------------------------------------------
__global__ __launch_bounds__(256) void gemm_phi_mfma(
    const ushort* __restrict__ A, const ushort* __restrict__ BT,
    const float* __restrict__ proj, ushort* __restrict__ OUT)
{
    __shared__ __align__(16) ushort uni[16384];  // main: As/Bs; epi: Aq[2][8][128][8]
    __shared__ __align__(16) ushort pjs[8192];   // proj bf16, B-layout [kg(8)][m(128)][8]
    const int t = threadIdx.x;

    for (int s = t; s < 1024; s += 256) {        // stage proj -> pjs
        int kgs = s >> 7, m = s & 127;
        const float* p = proj + (size_t)m * DH_ + kgs * 8;
        short8 v;
        #pragma unroll
        for (int j = 0; j < 8; ++j) v[j] = (short)f2b(p[j]);
        *(short8*)(pjs + (size_t)s * 8) = v;
    }

    const int bm = blockIdx.y * 128, bn = blockIdx.x * 128, h0 = blockIdx.x * 2;
    f32x4 acc[4][4];
    const f32x4 z4 = {0.f, 0.f, 0.f, 0.f};
    #pragma unroll
    for (int mt = 0; mt < 4; ++mt)
        #pragma unroll
        for (int nt = 0; nt < 4; ++nt) acc[mt][nt] = z4;

    mfma_gemm_g(A + (size_t)bm * HID_, BT + (size_t)bn * HID_,
                HID_, HID_, HID_, uni, uni + 4096, acc);

    const int w = t >> 6, lane = t & 63, wm = w >> 1, wn = w & 1;
    const int lr = lane & 15, rq = lane >> 4;

    // convert q quadrant -> Aq[head=wn] in A-operand layout [head][kg][row][8]
    #pragma unroll
    for (int mt = 0; mt < 4; ++mt)
        #pragma unroll
        for (int nt = 0; nt < 4; ++nt)
            #pragma unroll
            for (int p = 0; p < 4; ++p) {
                int row = wm * 64 + mt * 16 + rq * 4 + p;
                int d   = nt * 16 + lr;
                uni[(((size_t)wn * 8 + (d >> 3)) * 128 + row) * 8 + (d & 7)]
                    = f2b(acc[mt][nt][p]);
            }
    __syncthreads();

    const float ratio = 0.08838834764831845f;
    for (int hs = 0; hs < 2; ++hs) {
        f32x4 a2[4][4];
        #pragma unroll
        for (int mt = 0; mt < 4; ++mt)
            #pragma unroll
            for (int nt = 0; nt < 4; ++nt) a2[mt][nt] = z4;
        #pragma unroll
        for (int ks = 0; ks < 2; ++ks) {
            short8 av[4], bv[4];
            #pragma unroll
            for (int i = 0; i < 4; ++i)
                av[i] = *(const short8*)(uni +
                    (((size_t)hs*8 + ks*4 + rq) * 128 + wm*64 + i*16 + lr) * 8);
            #pragma unroll
            for (int i = 0; i < 4; ++i)
                bv[i] = *(const short8*)(pjs +
                    (((size_t)ks*4 + rq) * 128 + wn*64 + i*16 + lr) * 8);
            #pragma unroll
            for (int mt = 0; mt < 4; ++mt)
                #pragma unroll
                for (int nt = 0; nt < 4; ++nt)
                    a2[mt][nt] = __builtin_amdgcn_mfma_f32_16x16x32_bf16(
                        av[mt], bv[nt], a2[mt][nt], 0, 0, 0);
        }
        #pragma unroll
        for (int mt = 0; mt < 4; ++mt)
            #pragma unroll
            for (int nt = 0; nt < 4; ++nt)
                #pragma unroll
                for (int p = 0; p < 4; ++p) {
                    size_t rowg = bm + wm*64 + mt*16 + rq*4 + p;
                    int m = wn*64 + nt*16 + lr;
                    float v = fmaxf(a2[mt][nt][p] * ratio, 0.f) + 1e-3f;
                    OUT[(rowg * H_ + (h0 + hs)) * M_ + m] = f2b(v);
                }
    }
}

// ---------------------------------------------------------------------------
// Plain MFMA GEMM, bf16 out (V projection)
// ---------------------------------------------------------------------------
__global__ __launch_bounds__(256) void gemm_mfma_bf16(
    const ushort* __restrict__ A, const ushort* __restrict__ BT,
    ushort* __restrict__ C)
{
    __shared__ __align__(16) ushort As[4096], Bs[4096];
    const int bm = blockIdx.y * 128, bn = blockIdx.x * 128;
    f32x4 acc[4][4];
    const f32x4 z4 = {0.f, 0.f, 0.f, 0.f};
    #pragma unroll
    for (int mt = 0; mt < 4; ++mt)
        #pragma unroll
        for (int nt = 0; nt < 4; ++nt) acc[mt][nt] = z4;
    mfma_gemm_g(A + (size_t)bm * HID_, BT + (size_t)bn * HID_,
                HID_, HID_, HID_, As, Bs, acc);
    const int t = threadIdx.x, w = t >> 6, lane = t & 63;
    const int wm = w >> 1, wn = w & 1, lr = lane & 15, rq = lane >> 4;
    #pragma unroll
    for (int mt = 0; mt < 4; ++mt)
        #pragma unroll
        for (int nt = 0; nt < 4; ++nt)
            #pragma unroll
            for (int p = 0; p < 4; ++p) {
                size_t row = bm + wm*64 + mt*16 + rq*4 + p;
                int col = bn + wn*64 + nt*16 + lr;
                C[row * HID_ + col] = f2b(acc[mt][nt][p]);
            }
}

// ---------------------------------------------------------------------------
// Plain MFMA GEMM, f32 out (output projection)
// ---------------------------------------------------------------------------
__global__ __launch_bounds__(256) void gemm_mfma_f32(
    const ushort* __restrict__ A, const ushort* __restrict__ BT,
    float* __restrict__ C)
{
    __shared__ __align__(16) ushort As[4096], Bs[4096];
    const int bm = blockIdx.y * 128, bn = blockIdx.x * 128;
    f32x4 acc[4][4];
    const f32x4 z4 = {0.f, 0.f, 0.f, 0.f};
    #pragma unroll
    for (int mt = 0; mt < 4; ++mt)
        #pragma unroll
        for (int nt = 0; nt < 4; ++nt) acc[mt][nt] = z4;
    mfma_gemm_g(A + (size_t)bm * HID_, BT + (size_t)bn * HID_,
                HID_, HID_, HID_, As, Bs, acc);
    const int t = threadIdx.x, w = t >> 6, lane = t & 63;
    const int wm = w >> 1, wn = w & 1, lr = lane & 15, rq = lane >> 4;
    #pragma unroll
    for (int mt = 0; mt < 4; ++mt)
        #pragma unroll
        for (int nt = 0; nt < 4; ++nt)
            #pragma unroll
            for (int p = 0; p < 4; ++p) {
                size_t row = bm + wm*64 + mt*16 + rq*4 + p;
                int col = bn + wn*64 + nt*16 + lr;
                C[row * HID_ + col] = acc[mt][nt][p];
            }
}

// ---------------------------------------------------------------------------
// f32 -> bf16 elementwise convert (X inputs)
// ---------------------------------------------------------------------------
__global__ __launch_bounds__(256) void cvt_bf16(
    const float* __restrict__ X, ushort* __restrict__ Y, int n4)
{
    for (int i = blockIdx.x * 256 + threadIdx.x; i < n4; i += gridDim.x * 256) {
        float4 v = ((const float4*)X)[i];
        ushort4 o;
        o.x = f2b(v.x); o.y = f2b(v.y); o.z = f2b(v.z); o.w = f2b(v.w);
        ((ushort4*)Y)[i] = o;
    }
}

// ---------------------------------------------------------------------------
// W[k][n] f32 -> WT[n][k] bf16 (1024x1024), 64x64 tiles
// ---------------------------------------------------------------------------
__global__ __launch_bounds__(256) void wtrans(
    const float* __restrict__ W, ushort* __restrict__ WT)
{
    __shared__ float tile[64][65];
    const int k0 = blockIdx.y * 64, n0 = blockIdx.x * 64;
    const int t = threadIdx.x;
    for (int i = t; i < 1024; i += 256) {
        int r = i >> 4, c4 = i & 15;
        float4 v = *(const float4*)(W + (size_t)(k0 + r) * HID_ + n0 + c4 * 4);
        tile[r][c4*4+0] = v.x; tile[r][c4*4+1] = v.y;
        tile[r][c4*4+2] = v.z; tile[r][c4*4+3] = v.w;
    }
    __syncthreads();
    for (int i = t; i < 1024; i += 256) {
        int n = i >> 4, c4 = i & 15;
        ushort4 o;
        o.x = f2b(tile[c4*4+0][n]); o.y = f2b(tile[c4*4+1][n]);
        o.z = f2b(tile[c4*4+2][n]); o.w = f2b(tile[c4*4+3][n]);
        *(ushort4*)(WT + (size_t)(n0 + n) * HID_ + k0 + c4 * 4) = o;
    }
}

// ---------------------------------------------------------------------------
// KP [l][h][m] -> KPt[bh][m][l] bf16, 128x128 tiles, + per-m column sums
// (ksp[bh][lc][m], f32). XOR block swizzle pb = mq ^ (l>>3) makes both the
// strided column gathers and the row stores bank-conflict-free.
// grid (bh=64, lc=32).
// ---------------------------------------------------------------------------
__global__ __launch_bounds__(256) void kptrans_kernel(
    const ushort* __restrict__ KP, ushort* __restrict__ KPt,
    float* __restrict__ ksp)
{
    __shared__ __align__(16) ushort tile[128*128];   // 32KB, swizzled blocks
    const int bh = blockIdx.x, lc = blockIdx.y;
    const int b = bh >> 4, h = bh & 15;
    const int t = threadIdx.x;
    const size_t src = ((size_t)(b*L_ + lc*128) * H_ + h) * M_;

    #pragma unroll
    for (int it = 0; it < 8; ++it) {                 // load [l][m] swizzled
        int i = it*256 + t;
        int l = i >> 4, mq = i & 15;
        int pb = mq ^ (l >> 3);
        *(uint4*)&tile[l*128 + pb*8] =
            *(const uint4*)&KP[src + (size_t)l*(H_*M_) + mq*8];
    }
    __syncthreads();

    if (t < 128) {                                   // per-m partial sums
        float s = 0.f;
        for (int l = 0; l < 128; ++l) {
            int pb = (t >> 3) ^ (l >> 3);
            s += b2f(tile[l*128 + pb*8 + (t & 7)]);
        }
        ksp[((size_t)bh*32 + lc)*128 + t] = s;
    }

    #pragma unroll
    for (int it = 0; it < 8; ++it) {                 // transposed write-out
        int i = it*256 + t;
        int m = i >> 4, lq = i & 15;
        short8 v;
        #pragma unroll
        for (int j = 0; j < 8; ++j) {
            int l = lq*8 + j;
            int pb = (m >> 3) ^ lq;                  // l>>3 == lq (j<8)
            v[j] = (short)tile[l*128 + pb*8 + (m & 7)];
        }
        *(short8*)&KPt[((size_t)bh*128 + m)*L_ + lc*128 + lq*8] = v;
    }
}

// ---------------------------------------------------------------------------
// V [l][h][d] -> Vt[bh][d][l] bf16, 128x64 tiles. grid (bh=64, lc=32).
// ---------------------------------------------------------------------------
__global__ __launch_bounds__(256) void vtrans_kernel(
    const ushort* __restrict__ V, ushort* __restrict__ Vt)
{
    __shared__ __align__(16) ushort tile[128*64];    // 16KB, swizzled blocks
    const int bh = blockIdx.x, lc = blockIdx.y;
    const int b = bh >> 4, h = bh & 15;
    const int t = threadIdx.x;
    const size_t src = ((size_t)(b*L_ + lc*128) * H_ + h) * DH_;

    #pragma unroll
    for (int it = 0; it < 4; ++it) {                 // load [l][d] swizzled
        int i = it*256 + t;
        int l = i >> 3, mq = i & 7;
        int pb = mq ^ ((l >> 3) & 7);
        *(uint4*)&tile[l*64 + pb*8] =
            *(const uint4*)&V[src + (size_t)l*(H_*DH_) + mq*8];
    }
    __syncthreads();

    #pragma unroll
    for (int it = 0; it < 4; ++it) {                 // transposed write-out
        int i = it*256 + t;
        int d = i >> 4, lq = i & 15;
        short8 v;
        #pragma unroll
        for (int j = 0; j < 8; ++j) {
            int l = lq*8 + j;
            int pb = (d >> 3) ^ (lq & 7);
            v[j] = (short)tile[l*64 + pb*8 + (d & 7)];
        }
        *(short8*)&Vt[((size_t)bh*64 + d)*L_ + lc*128 + lq*8] = v;
    }
}

// ---------------------------------------------------------------------------
// kvs via MFMA: per (bh, part), C[d(64)][m(128)] += sum over 512 l of
// Vt[d][l]*KPt[m][l]. A=Vt (64 rows), BT=KPt (128 rows), K=512, k-contig.
// 4 waves: wave w quadrant rows (w>>1)*32, cols (w&1)*64; acc[2][4].
// Partials KVSP[part][bh][d][m] f32. grid (bh=64, part=8).
// ---------------------------------------------------------------------------
__global__ __launch_bounds__(256) void kvs_mfma(
    const ushort* __restrict__ Vt, const ushort* __restrict__ KPt,
    float* __restrict__ KVSP)
{
    __shared__ __align__(16) ushort As[2048], Bs[4096];  // 4KB + 8KB
    const int bh = blockIdx.x, part = blockIdx.y;
    const ushort* A  = Vt  + (size_t)bh * 64  * L_ + part * 512;
    const ushort* BT = KPt + (size_t)bh * 128 * L_ + part * 512;
    const int t = threadIdx.x, w = t >> 6, lane = t & 63;
    const int wm = w >> 1, wn = w & 1, kg = lane >> 4, lr = lane & 15;
    const ushort* a0 = A  + (size_t)lane * L_ + w * 8;
    const ushort* b0 = BT + (size_t)lane * L_ + w * 8;
    const ushort* b1 = BT + (size_t)(64 + lane) * L_ + w * 8;
    ushort* lA0 = As + (size_t)(w * 64) * 8;
    ushort* lB0 = Bs + (size_t)(w * 128) * 8;
    ushort* lB1 = Bs + (size_t)(w * 128 + 64) * 8;

    f32x4 acc[2][4];
    const f32x4 z4 = {0.f, 0.f, 0.f, 0.f};
    #pragma unroll
    for (int mt = 0; mt < 2; ++mt)
        #pragma unroll
        for (int nt = 0; nt < 4; ++nt) acc[mt][nt] = z4;

    for (int k0 = 0; k0 < 512; k0 += 32) {
        gld16(lA0, a0 + k0); gld16(lB0, b0 + k0); gld16(lB1, b1 + k0);
        __syncthreads();
        short8 av[2], bv[4];
        #pragma unroll
        for (int i = 0; i < 2; ++i)
            av[i] = *(const short8*)(As + ((size_t)kg*64 + wm*32 + i*16 + lr) * 8);
        #pragma unroll
        for (int i = 0; i < 4; ++i)
            bv[i] = *(const short8*)(Bs + ((size_t)kg*128 + wn*64 + i*16 + lr) * 8);
        #pragma unroll
        for (int mt = 0; mt < 2; ++mt)
            #pragma unroll
            for (int nt = 0; nt < 4; ++nt)
                acc[mt][nt] = __builtin_amdgcn_mfma_f32_16x16x32_bf16(
                    av[mt], bv[nt], acc[mt][nt], 0, 0, 0);
        __syncthreads();
    }

    const int rq = lane >> 4;
    #pragma unroll
    for (int mt = 0; mt < 2; ++mt)
        #pragma unroll
        for (int nt = 0; nt < 4; ++nt)
            #pragma unroll
            for (int p = 0; p < 4; ++p) {
                int row = wm*32 + mt*16 + rq*4 + p;        // d
                int col = wn*64 + nt*16 + lr;              // m
                KVSP[(((size_t)part*64 + bh)*64 + row)*128 + col]
                    = acc[mt][nt][p];
            }
}

// ---------------------------------------------------------------------------
// kvs_reduce: sum 8 KVS partials + 32 ksp partials -> bf16
// KVSt[bh][d][m] (d<64) = kvs; [64][m] = ks_sum; [65..127][m] = 0
// ---------------------------------------------------------------------------
__global__ __launch_bounds__(256) void kvs_reduce_kernel(
    const float* __restrict__ KVSP, const float* __restrict__ ksp,
    ushort* __restrict__ KVSt)
{
    const int bh = blockIdx.x;
    for (int i = threadIdx.x; i < 128*128; i += 256) {
        int d = i >> 7, m = i & 127;
        ushort v = 0;
        if (d < 64) {
            float s = 0.f;
            #pragma unroll
            for (int p = 0; p < 8; ++p)
                s += KVSP[(((size_t)p*64 + bh)*64 + d)*128 + m];
            v = f2b(s);
        } else if (d == 64) {
            float s = 0.f;
            #pragma unroll
            for (int c = 0; c < 32; ++c)
                s += ksp[((size_t)bh*32 + c)*128 + m];
            v = f2b(s);
        }
        KVSt[(size_t)bh * 16384 + i] = v;
    }
}

// ---------------------------------------------------------------------------
// numden: per (b,h), 128-row tile: [QP rows, K=128 m] x KVSt[128][128].
// Output cols 0..63 = num, col 64 = den -> ATT = num/den (bf16) directly.
// grid (bh=64, L/128=32).
// ---------------------------------------------------------------------------
__global__ __launch_bounds__(256) void numden_mfma(
    const ushort* __restrict__ QP, const ushort* __restrict__ KVSt,
    ushort* __restrict__ ATT)
{
    __shared__ __align__(16) ushort As[4096], Bs[4096];
    __shared__ float sden[128];
    const int bh = blockIdx.x, b = bh >> 4, h = bh & 15;
    const int l0 = blockIdx.y * 128;
    const ushort* Abase = QP + ((size_t)(b * L_ + l0) * H_ + h) * M_;
    const ushort* Bbase = KVSt + (size_t)bh * 16384;

    f32x4 acc[4][4];
    const f32x4 z4 = {0.f, 0.f, 0.f, 0.f};
    #pragma unroll
    for (int mt = 0; mt < 4; ++mt)
        #pragma unroll
        for (int nt = 0; nt < 4; ++nt) acc[mt][nt] = z4;

    mfma_gemm_g(Abase, Bbase, H_*M_, 128, 128, As, Bs, acc);

    const int t = threadIdx.x, w = t >> 6, lane = t & 63;
    const int wm = w >> 1, wn = w & 1, lr = lane & 15, rq = lane >> 4;

    if (wn == 1 && lr == 0) {       // col 64 = den
        #pragma unroll
        for (int mt = 0; mt < 4; ++mt)
            #pragma unroll
            for (int p = 0; p < 4; ++p)
                sden[wm*64 + mt*16 + rq*4 + p] = acc[mt][0][p];
    }
    __syncthreads();

    if (wn == 0) {
        #pragma unroll
        for (int mt = 0; mt < 4; ++mt) {
            #pragma unroll
            for (int p = 0; p < 4; ++p) {
                int row = wm*64 + mt*16 + rq*4 + p;
                float den = fmaxf(sden[row], 1e-10f);
                float rden = 1.0f / den;
                size_t gbase = (size_t)(b * L_ + l0 + row) * HID_ + h * DH_;
                #pragma unroll
                for (int nt = 0; nt < 4; ++nt)
                    ATT[gbase + nt*16 + lr] = f2b(acc[mt][nt][p] * rden);
            }
        }
    }
}

// ---------------------------------------------------------------------------
extern "C" void kernel_launch(void* const* d_in, const int* in_sizes, int n_in,
                              void* d_out, int out_size, void* d_ws, size_t ws_size,
                              hipStream_t stream)
{
    const float* Xq = (const float*)d_in[0];
    const float* Xs = (const float*)d_in[1];
    const float* Wq = (const float*)d_in[2];
    const float* Wk = (const float*)d_in[3];
    const float* Wv = (const float*)d_in[4];
    const float* Wo = (const float*)d_in[5];
    const float* Pj = (const float*)d_in[6];
    float* out = (float*)d_out;

    // Workspace layout (MB-aligned, audited disjoint per stage / safe alias):
    //   WqT..WoT [0,8)  Xqb [8,40)  Xsb [40,72)  QPb [72,136)
    //   KPb [136,200)   Vb [200,232)
    //   KPt  [8,72)    alias Xqb+Xsb  (dead after gemms)
    //   Vt   [136,168) alias KPb-lo   (KPb dead after kptrans)
    //   KVSP [168,184) alias KPb-mid
    //   KVSt [184,186) alias KPb-hi
    //   ksp  [0,1)     alias WqT      (dead after Q-gemm)
    //   ATT  [200,232) alias Vb       (dead after vtrans)
    char* ws = (char*)d_ws;
    ushort* WqT = (ushort*)(ws + 0);
    ushort* WkT = (ushort*)(ws + 2097152);
    ushort* WvT = (ushort*)(ws + 4194304);
    ushort* WoT = (ushort*)(ws + 6291456);
    ushort* Xqb = (ushort*)(ws + 8388608);
    ushort* Xsb = (ushort*)(ws + 41943040);
    ushort* QPb = (ushort*)(ws + 75497472);
    ushort* KPb = (ushort*)(ws + 142606336);
    ushort* Vb  = (ushort*)(ws + 209715200);
    ushort* KPt = (ushort*)(ws + 8388608);        // 64MB
    ushort* Vt  = (ushort*)(ws + 142606336);      // 32MB
    float*  KVSP = (float*)(ws + 176160768);      // 16MB
    ushort* KVSt = (ushort*)(ws + 192937984);     // 2MB
    float*  ksp  = (float*)(ws + 0);              // 1MB
    ushort* ATT  = Vb;

    dim3 tb(256);

    cvt_bf16<<<4096, tb, 0, stream>>>(Xq, Xqb, BL_*HID_/4);
    cvt_bf16<<<4096, tb, 0, stream>>>(Xs, Xsb, BL_*HID_/4);
    wtrans<<<dim3(16,16), tb, 0, stream>>>(Wq, WqT);
    wtrans<<<dim3(16,16), tb, 0, stream>>>(Wk, WkT);
    wtrans<<<dim3(16,16), tb, 0, stream>>>(Wv, WvT);
    wtrans<<<dim3(16,16), tb, 0, stream>>>(Wo, WoT);

    gemm_phi_mfma<<<dim3(8, 128), tb, 0, stream>>>(Xqb, WqT, Pj, QPb);
    gemm_phi_mfma<<<dim3(8, 128), tb, 0, stream>>>(Xsb, WkT, Pj, KPb);
    gemm_mfma_bf16<<<dim3(8, 128), tb, 0, stream>>>(Xsb, WvT, Vb);

    kptrans_kernel<<<dim3(64, 32), tb, 0, stream>>>(KPb, KPt, ksp);
    vtrans_kernel<<<dim3(64, 32), tb, 0, stream>>>(Vb, Vt);

    kvs_mfma<<<dim3(64, 8), tb, 0, stream>>>(Vt, KPt, KVSP);
    kvs_reduce_kernel<<<64, tb, 0, stream>>>(KVSP, ksp, KVSt);

    numden_mfma<<<dim3(B_*H_, L_/128), tb, 0, stream>>>(QPb, KVSt, ATT);

    gemm_mfma_f32<<<dim3(8, 128), tb, 0, stream>>>(ATT, WoT, out);
    (void)in_sizes; (void)n_in; (void)out_size; (void)ws_size;
}

// Round 2
// 613.067 us; speedup vs baseline: 1.2195x; 1.0194x over previous
//
#include <hip/hip_runtime.h>
#include <hip/hip_bf16.h>

// Performer / FAVOR+ noncausal attention. ALL inputs + output FLOAT32.
// Intermediates bf16/f32. MFMA (16x16x32 bf16) for GEMMs + fused num/den.
// This revision:
//  - gemm_phi LDS 48K->32K (sequential-head phi epilogue) => 4 blocks/CU,
//    grid 1024 fully resident (was 3 blocks/CU => 768 + ragged tail).
//  - XCD-chunked bijective blockIdx swizzle on the three 1024-block GEMMs
//    (A-panel was fetched on all 8 XCD L2s; now 1 XCD per panel).
#define B_   4
#define L_   4096
#define HID_ 1024
#define H_   16
#define DH_  64
#define M_   128
#define BL_  (B_*L_)        // 16384
#define NROW (BL_*H_)       // 262144

using short8 = __attribute__((ext_vector_type(8))) short;
using f32x4  = __attribute__((ext_vector_type(4))) float;

__device__ __forceinline__ float b2f(ushort s) {
    return __builtin_bit_cast(float, (unsigned int)s << 16);
}
__device__ __forceinline__ ushort f2b(float f) {  // RNE
    unsigned int u = __builtin_bit_cast(unsigned int, f);
    u += 0x7fffu + ((u >> 16) & 1u);
    return (ushort)(u >> 16);
}

// async global->LDS, 16B per lane; LDS dest = wave-uniform base + lane*16
__device__ __forceinline__ void gld16(void* lds, const void* g) {
    __builtin_amdgcn_global_load_lds(
        (const __attribute__((address_space(1))) unsigned int*)g,
        (__attribute__((address_space(3))) unsigned int*)lds, 16, 0, 0);
}

// XCD-chunked bijective remap for grid (8,128) = 1024 blocks (1024%8==0).
// HW round-robins dispatch id over 8 XCDs; remap so each XCD owns 16
// contiguous row-panels with all 8 column blocks (A-panel L2 locality).
__device__ __forceinline__ void xcd_swz_8x128(int& bx, int& by) {
    int orig = (int)blockIdx.x + ((int)blockIdx.y << 3);
    int nu = ((orig & 7) << 7) + (orig >> 3);
    bx = nu & 7; by = nu >> 3;
}

// ---------------------------------------------------------------------------
// Generalized 128x128-tile MFMA K-loop. A[row][k] stride sA, BT[col][k] stride
// sB (both k-contiguous, 16B-aligned). LDS As/Bs: [kg(4)][r(128)][8] (8KB ea).
// 256 thr / 4 waves; wave w: rows (w>>1)*64.., cols (w&1)*64..; acc[4][4].
// ---------------------------------------------------------------------------
__device__ __forceinline__ void mfma_gemm_g(
    const ushort* __restrict__ A, const ushort* __restrict__ BT,
    int sA, int sB, int K, ushort* As, ushort* Bs, f32x4 acc[4][4])
{
    const int t = threadIdx.x, w = t >> 6, lane = t & 63;
    const int wm = w >> 1, wn = w & 1, kg = lane >> 4, lr = lane & 15;
    const ushort* a0 = A  + (size_t)lane * sA + w * 8;
    const ushort* a1 = A  + (size_t)(64 + lane) * sA + w * 8;
    const ushort* b0 = BT + (size_t)lane * sB + w * 8;
    const ushort* b1 = BT + (size_t)(64 + lane) * sB + w * 8;
    ushort* lA0 = As + (size_t)(w * 128) * 8;
    ushort* lA1 = As + (size_t)(w * 128 + 64) * 8;
    ushort* lB0 = Bs + (size_t)(w * 128) * 8;
    ushort* lB1 = Bs + (size_t)(w * 128 + 64) * 8;

    for (int k0 = 0; k0 < K; k0 += 32) {
        gld16(lA0, a0 + k0); gld16(lA1, a1 + k0);
        gld16(lB0, b0 + k0); gld16(lB1, b1 + k0);
        __syncthreads();
        short8 av[4], bv[4];
        #pragma unroll
        for (int i = 0; i < 4; ++i)
            av[i] = *(const short8*)(As + ((size_t)kg*128 + wm*64 + i*16 + lr) * 8);
        #pragma unroll
        for (int i = 0; i < 4; ++i)
            bv[i] = *(const short8*)(Bs + ((size_t)kg*128 + wn*64 + i*16 + lr) * 8);
        #pragma unroll
        for (int mt = 0; mt < 4; ++mt)
            #pragma unroll
            for (int nt = 0; nt < 4; ++nt)
                acc[mt][nt] = __builtin_amdgcn_mfma_f32_16x16x32_bf16(
                    av[mt], bv[nt], acc[mt][nt], 0, 0, 0);
        __syncthreads();
    }
}

// ---------------------------------------------------------------------------
// Fused QK projection + phi (all-MFMA).
// grid (HID/128=8, BL/128=128); block covers heads h0=2*bx, h0+1.
// LDS 32KB total: uni 16KB (As/Bs main; Aq one-head epi), pjs 16KB.
// ---------------------------------------------------------------------------
__global__ __launch_bounds__(256) void gemm_phi_mfma(
    const ushort* __restrict__ A, const ushort* __restrict__ BT,
    const float* __restrict__ proj, ushort* __restrict__ OUT)
{
    __shared__ __align__(16) ushort uni[8192];   // main: As/Bs; epi: Aq[8][128][8]
    __shared__ __align__(16) ushort pjs[8192];   // proj bf16, B-layout [kg(8)][m(128)][8]
    const int t = threadIdx.x;

    for (int s = t; s < 1024; s += 256) {        // stage proj -> pjs
        int kgs = s >> 7, m = s & 127;
        const float* p = proj + (size_t)m * DH_ + kgs * 8;
        short8 v;
        #pragma unroll
        for (int j = 0; j < 8; ++j) v[j] = (short)f2b(p[j]);
        *(short8*)(pjs + (size_t)s * 8) = v;
    }

    int bx, by; xcd_swz_8x128(bx, by);
    const int bm = by * 128, bn = bx * 128, h0 = bx * 2;
    f32x4 acc[4][4];
    const f32x4 z4 = {0.f, 0.f, 0.f, 0.f};
    #pragma unroll
    for (int mt = 0; mt < 4; ++mt)
        #pragma unroll
        for (int nt = 0; nt < 4; ++nt) acc[mt][nt] = z4;

    mfma_gemm_g(A + (size_t)bm * HID_, BT + (size_t)bn * HID_,
                HID_, HID_, HID_, uni, uni + 4096, acc);

    const int w = t >> 6, lane = t & 63, wm = w >> 1, wn = w & 1;
    const int lr = lane & 15, rq = lane >> 4;

    const float ratio = 0.08838834764831845f;
    for (int hs = 0; hs < 2; ++hs) {
        // convert head-hs quadrants -> Aq in A-operand layout [kg][row][8]
        // (waves with wn==hs own the columns of head hs; As/Bs dead here)
        if (wn == hs) {
            #pragma unroll
            for (int mt = 0; mt < 4; ++mt)
                #pragma unroll
                for (int nt = 0; nt < 4; ++nt)
                    #pragma unroll
                    for (int p = 0; p < 4; ++p) {
                        int row = wm * 64 + mt * 16 + rq * 4 + p;
                        int d   = nt * 16 + lr;
                        uni[(((size_t)(d >> 3)) * 128 + row) * 8 + (d & 7)]
                            = f2b(acc[mt][nt][p]);
                    }
        }
        __syncthreads();

        f32x4 a2[4][4];
        #pragma unroll
        for (int mt = 0; mt < 4; ++mt)
            #pragma unroll
            for (int nt = 0; nt < 4; ++nt) a2[mt][nt] = z4;
        #pragma unroll
        for (int ks = 0; ks < 2; ++ks) {
            short8 av[4], bv[4];
            #pragma unroll
            for (int i = 0; i < 4; ++i)
                av[i] = *(const short8*)(uni +
                    (((size_t)ks*4 + rq) * 128 + wm*64 + i*16 + lr) * 8);
            #pragma unroll
            for (int i = 0; i < 4; ++i)
                bv[i] = *(const short8*)(pjs +
                    (((size_t)ks*4 + rq) * 128 + wn*64 + i*16 + lr) * 8);
            #pragma unroll
            for (int mt = 0; mt < 4; ++mt)
                #pragma unroll
                for (int nt = 0; nt < 4; ++nt)
                    a2[mt][nt] = __builtin_amdgcn_mfma_f32_16x16x32_bf16(
                        av[mt], bv[nt], a2[mt][nt], 0, 0, 0);
        }
        #pragma unroll
        for (int mt = 0; mt < 4; ++mt)
            #pragma unroll
            for (int nt = 0; nt < 4; ++nt)
                #pragma unroll
                for (int p = 0; p < 4; ++p) {
                    size_t rowg = bm + wm*64 + mt*16 + rq*4 + p;
                    int m = wn*64 + nt*16 + lr;
                    float v = fmaxf(a2[mt][nt][p] * ratio, 0.f) + 1e-3f;
                    OUT[(rowg * H_ + (h0 + hs)) * M_ + m] = f2b(v);
                }
        __syncthreads();   // Aq reused next hs iteration
    }
}

// ---------------------------------------------------------------------------
// Plain MFMA GEMM, bf16 out (V projection)
// ---------------------------------------------------------------------------
__global__ __launch_bounds__(256) void gemm_mfma_bf16(
    const ushort* __restrict__ A, const ushort* __restrict__ BT,
    ushort* __restrict__ C)
{
    __shared__ __align__(16) ushort As[4096], Bs[4096];
    int bx, by; xcd_swz_8x128(bx, by);
    const int bm = by * 128, bn = bx * 128;
    f32x4 acc[4][4];
    const f32x4 z4 = {0.f, 0.f, 0.f, 0.f};
    #pragma unroll
    for (int mt = 0; mt < 4; ++mt)
        #pragma unroll
        for (int nt = 0; nt < 4; ++nt) acc[mt][nt] = z4;
    mfma_gemm_g(A + (size_t)bm * HID_, BT + (size_t)bn * HID_,
                HID_, HID_, HID_, As, Bs, acc);
    const int t = threadIdx.x, w = t >> 6, lane = t & 63;
    const int wm = w >> 1, wn = w & 1, lr = lane & 15, rq = lane >> 4;
    #pragma unroll
    for (int mt = 0; mt < 4; ++mt)
        #pragma unroll
        for (int nt = 0; nt < 4; ++nt)
            #pragma unroll
            for (int p = 0; p < 4; ++p) {
                size_t row = bm + wm*64 + mt*16 + rq*4 + p;
                int col = bn + wn*64 + nt*16 + lr;
                C[row * HID_ + col] = f2b(acc[mt][nt][p]);
            }
}

// ---------------------------------------------------------------------------
// Plain MFMA GEMM, f32 out (output projection)
// ---------------------------------------------------------------------------
__global__ __launch_bounds__(256) void gemm_mfma_f32(
    const ushort* __restrict__ A, const ushort* __restrict__ BT,
    float* __restrict__ C)
{
    __shared__ __align__(16) ushort As[4096], Bs[4096];
    int bx, by; xcd_swz_8x128(bx, by);
    const int bm = by * 128, bn = bx * 128;
    f32x4 acc[4][4];
    const f32x4 z4 = {0.f, 0.f, 0.f, 0.f};
    #pragma unroll
    for (int mt = 0; mt < 4; ++mt)
        #pragma unroll
        for (int nt = 0; nt < 4; ++nt) acc[mt][nt] = z4;
    mfma_gemm_g(A + (size_t)bm * HID_, BT + (size_t)bn * HID_,
                HID_, HID_, HID_, As, Bs, acc);
    const int t = threadIdx.x, w = t >> 6, lane = t & 63;
    const int wm = w >> 1, wn = w & 1, lr = lane & 15, rq = lane >> 4;
    #pragma unroll
    for (int mt = 0; mt < 4; ++mt)
        #pragma unroll
        for (int nt = 0; nt < 4; ++nt)
            #pragma unroll
            for (int p = 0; p < 4; ++p) {
                size_t row = bm + wm*64 + mt*16 + rq*4 + p;
                int col = bn + wn*64 + nt*16 + lr;
                C[row * HID_ + col] = acc[mt][nt][p];
            }
}

// ---------------------------------------------------------------------------
// f32 -> bf16 elementwise convert (X inputs)
// ---------------------------------------------------------------------------
__global__ __launch_bounds__(256) void cvt_bf16(
    const float* __restrict__ X, ushort* __restrict__ Y, int n4)
{
    for (int i = blockIdx.x * 256 + threadIdx.x; i < n4; i += gridDim.x * 256) {
        float4 v = ((const float4*)X)[i];
        ushort4 o;
        o.x = f2b(v.x); o.y = f2b(v.y); o.z = f2b(v.z); o.w = f2b(v.w);
        ((ushort4*)Y)[i] = o;
    }
}

// ---------------------------------------------------------------------------
// W[k][n] f32 -> WT[n][k] bf16 (1024x1024), 64x64 tiles
// ---------------------------------------------------------------------------
__global__ __launch_bounds__(256) void wtrans(
    const float* __restrict__ W, ushort* __restrict__ WT)
{
    __shared__ float tile[64][65];
    const int k0 = blockIdx.y * 64, n0 = blockIdx.x * 64;
    const int t = threadIdx.x;
    for (int i = t; i < 1024; i += 256) {
        int r = i >> 4, c4 = i & 15;
        float4 v = *(const float4*)(W + (size_t)(k0 + r) * HID_ + n0 + c4 * 4);
        tile[r][c4*4+0] = v.x; tile[r][c4*4+1] = v.y;
        tile[r][c4*4+2] = v.z; tile[r][c4*4+3] = v.w;
    }
    __syncthreads();
    for (int i = t; i < 1024; i += 256) {
        int n = i >> 4, c4 = i & 15;
        ushort4 o;
        o.x = f2b(tile[c4*4+0][n]); o.y = f2b(tile[c4*4+1][n]);
        o.z = f2b(tile[c4*4+2][n]); o.w = f2b(tile[c4*4+3][n]);
        *(ushort4*)(WT + (size_t)(n0 + n) * HID_ + k0 + c4 * 4) = o;
    }
}

// ---------------------------------------------------------------------------
// KP [l][h][m] -> KPt[bh][m][l] bf16, 128x128 tiles, + per-m column sums
// (ksp[bh][lc][m], f32). XOR block swizzle pb = mq ^ (l>>3) makes both the
// strided column gathers and the row stores bank-conflict-free.
// grid (bh=64, lc=32).
// ---------------------------------------------------------------------------
__global__ __launch_bounds__(256) void kptrans_kernel(
    const ushort* __restrict__ KP, ushort* __restrict__ KPt,
    float* __restrict__ ksp)
{
    __shared__ __align__(16) ushort tile[128*128];   // 32KB, swizzled blocks
    const int bh = blockIdx.x, lc = blockIdx.y;
    const int b = bh >> 4, h = bh & 15;
    const int t = threadIdx.x;
    const size_t src = ((size_t)(b*L_ + lc*128) * H_ + h) * M_;

    #pragma unroll
    for (int it = 0; it < 8; ++it) {                 // load [l][m] swizzled
        int i = it*256 + t;
        int l = i >> 4, mq = i & 15;
        int pb = mq ^ (l >> 3);
        *(uint4*)&tile[l*128 + pb*8] =
            *(const uint4*)&KP[src + (size_t)l*(H_*M_) + mq*8];
    }
    __syncthreads();

    if (t < 128) {                                   // per-m partial sums
        float s = 0.f;
        for (int l = 0; l < 128; ++l) {
            int pb = (t >> 3) ^ (l >> 3);
            s += b2f(tile[l*128 + pb*8 + (t & 7)]);
        }
        ksp[((size_t)bh*32 + lc)*128 + t] = s;
    }

    #pragma unroll
    for (int it = 0; it < 8; ++it) {                 // transposed write-out
        int i = it*256 + t;
        int m = i >> 4, lq = i & 15;
        short8 v;
        #pragma unroll
        for (int j = 0; j < 8; ++j) {
            int l = lq*8 + j;
            int pb = (m >> 3) ^ lq;                  // l>>3 == lq (j<8)
            v[j] = (short)tile[l*128 + pb*8 + (m & 7)];
        }
        *(short8*)&KPt[((size_t)bh*128 + m)*L_ + lc*128 + lq*8] = v;
    }
}

// ---------------------------------------------------------------------------
// V [l][h][d] -> Vt[bh][d][l] bf16, 128x64 tiles. grid (bh=64, lc=32).
// ---------------------------------------------------------------------------
__global__ __launch_bounds__(256) void vtrans_kernel(
    const ushort* __restrict__ V, ushort* __restrict__ Vt)
{
    __shared__ __align__(16) ushort tile[128*64];    // 16KB, swizzled blocks
    const int bh = blockIdx.x, lc = blockIdx.y;
    const int b = bh >> 4, h = bh & 15;
    const int t = threadIdx.x;
    const size_t src = ((size_t)(b*L_ + lc*128) * H_ + h) * DH_;

    #pragma unroll
    for (int it = 0; it < 4; ++it) {                 // load [l][d] swizzled
        int i = it*256 + t;
        int l = i >> 3, mq = i & 7;
        int pb = mq ^ ((l >> 3) & 7);
        *(uint4*)&tile[l*64 + pb*8] =
            *(const uint4*)&V[src + (size_t)l*(H_*DH_) + mq*8];
    }
    __syncthreads();

    #pragma unroll
    for (int it = 0; it < 4; ++it) {                 // transposed write-out
        int i = it*256 + t;
        int d = i >> 4, lq = i & 15;
        short8 v;
        #pragma unroll
        for (int j = 0; j < 8; ++j) {
            int l = lq*8 + j;
            int pb = (d >> 3) ^ (lq & 7);
            v[j] = (short)tile[l*64 + pb*8 + (d & 7)];
        }
        *(short8*)&Vt[((size_t)bh*64 + d)*L_ + lc*128 + lq*8] = v;
    }
}

// ---------------------------------------------------------------------------
// kvs via MFMA: per (bh, part), C[d(64)][m(128)] += sum over 512 l of
// Vt[d][l]*KPt[m][l]. A=Vt (64 rows), BT=KPt (128 rows), K=512, k-contig.
// 4 waves: wave w quadrant rows (w>>1)*32, cols (w&1)*64; acc[2][4].
// Partials KVSP[part][bh][d][m] f32. grid (bh=64, part=8).
// ---------------------------------------------------------------------------
__global__ __launch_bounds__(256) void kvs_mfma(
    const ushort* __restrict__ Vt, const ushort* __restrict__ KPt,
    float* __restrict__ KVSP)
{
    __shared__ __align__(16) ushort As[2048], Bs[4096];  // 4KB + 8KB
    const int bh = blockIdx.x, part = blockIdx.y;
    const ushort* A  = Vt  + (size_t)bh * 64  * L_ + part * 512;
    const ushort* BT = KPt + (size_t)bh * 128 * L_ + part * 512;
    const int t = threadIdx.x, w = t >> 6, lane = t & 63;
    const int wm = w >> 1, wn = w & 1, kg = lane >> 4, lr = lane & 15;
    const ushort* a0 = A  + (size_t)lane * L_ + w * 8;
    const ushort* b0 = BT + (size_t)lane * L_ + w * 8;
    const ushort* b1 = BT + (size_t)(64 + lane) * L_ + w * 8;
    ushort* lA0 = As + (size_t)(w * 64) * 8;
    ushort* lB0 = Bs + (size_t)(w * 128) * 8;
    ushort* lB1 = Bs + (size_t)(w * 128 + 64) * 8;

    f32x4 acc[2][4];
    const f32x4 z4 = {0.f, 0.f, 0.f, 0.f};
    #pragma unroll
    for (int mt = 0; mt < 2; ++mt)
        #pragma unroll
        for (int nt = 0; nt < 4; ++nt) acc[mt][nt] = z4;

    for (int k0 = 0; k0 < 512; k0 += 32) {
        gld16(lA0, a0 + k0); gld16(lB0, b0 + k0); gld16(lB1, b1 + k0);
        __syncthreads();
        short8 av[2], bv[4];
        #pragma unroll
        for (int i = 0; i < 2; ++i)
            av[i] = *(const short8*)(As + ((size_t)kg*64 + wm*32 + i*16 + lr) * 8);
        #pragma unroll
        for (int i = 0; i < 4; ++i)
            bv[i] = *(const short8*)(Bs + ((size_t)kg*128 + wn*64 + i*16 + lr) * 8);
        #pragma unroll
        for (int mt = 0; mt < 2; ++mt)
            #pragma unroll
            for (int nt = 0; nt < 4; ++nt)
                acc[mt][nt] = __builtin_amdgcn_mfma_f32_16x16x32_bf16(
                    av[mt], bv[nt], acc[mt][nt], 0, 0, 0);
        __syncthreads();
    }

    const int rq = lane >> 4;
    #pragma unroll
    for (int mt = 0; mt < 2; ++mt)
        #pragma unroll
        for (int nt = 0; nt < 4; ++nt)
            #pragma unroll
            for (int p = 0; p < 4; ++p) {
                int row = wm*32 + mt*16 + rq*4 + p;        // d
                int col = wn*64 + nt*16 + lr;              // m
                KVSP[(((size_t)part*64 + bh)*64 + row)*128 + col]
                    = acc[mt][nt][p];
            }
}

// ---------------------------------------------------------------------------
// kvs_reduce: sum 8 KVS partials + 32 ksp partials -> bf16
// KVSt[bh][d][m] (d<64) = kvs; [64][m] = ks_sum; [65..127][m] = 0
// ---------------------------------------------------------------------------
__global__ __launch_bounds__(256) void kvs_reduce_kernel(
    const float* __restrict__ KVSP, const float* __restrict__ ksp,
    ushort* __restrict__ KVSt)
{
    const int bh = blockIdx.x;
    for (int i = threadIdx.x; i < 128*128; i += 256) {
        int d = i >> 7, m = i & 127;
        ushort v = 0;
        if (d < 64) {
            float s = 0.f;
            #pragma unroll
            for (int p = 0; p < 8; ++p)
                s += KVSP[(((size_t)p*64 + bh)*64 + d)*128 + m];
            v = f2b(s);
        } else if (d == 64) {
            float s = 0.f;
            #pragma unroll
            for (int c = 0; c < 32; ++c)
                s += ksp[((size_t)bh*32 + c)*128 + m];
            v = f2b(s);
        }
        KVSt[(size_t)bh * 16384 + i] = v;
    }
}

// ---------------------------------------------------------------------------
// numden: per (b,h), 128-row tile: [QP rows, K=128 m] x KVSt[128][128].
// Output cols 0..63 = num, col 64 = den -> ATT = num/den (bf16) directly.
// grid (bh=64, L/128=32).
// ---------------------------------------------------------------------------
__global__ __launch_bounds__(256) void numden_mfma(
    const ushort* __restrict__ QP, const ushort* __restrict__ KVSt,
    ushort* __restrict__ ATT)
{
    __shared__ __align__(16) ushort As[4096], Bs[4096];
    __shared__ float sden[128];
    const int bh = blockIdx.x, b = bh >> 4, h = bh & 15;
    const int l0 = blockIdx.y * 128;
    const ushort* Abase = QP + ((size_t)(b * L_ + l0) * H_ + h) * M_;
    const ushort* Bbase = KVSt + (size_t)bh * 16384;

    f32x4 acc[4][4];
    const f32x4 z4 = {0.f, 0.f, 0.f, 0.f};
    #pragma unroll
    for (int mt = 0; mt < 4; ++mt)
        #pragma unroll
        for (int nt = 0; nt < 4; ++nt) acc[mt][nt] = z4;

    mfma_gemm_g(Abase, Bbase, H_*M_, 128, 128, As, Bs, acc);

    const int t = threadIdx.x, w = t >> 6, lane = t & 63;
    const int wm = w >> 1, wn = w & 1, lr = lane & 15, rq = lane >> 4;

    if (wn == 1 && lr == 0) {       // col 64 = den
        #pragma unroll
        for (int mt = 0; mt < 4; ++mt)
            #pragma unroll
            for (int p = 0; p < 4; ++p)
                sden[wm*64 + mt*16 + rq*4 + p] = acc[mt][0][p];
    }
    __syncthreads();

    if (wn == 0) {
        #pragma unroll
        for (int mt = 0; mt < 4; ++mt) {
            #pragma unroll
            for (int p = 0; p < 4; ++p) {
                int row = wm*64 + mt*16 + rq*4 + p;
                float den = fmaxf(sden[row], 1e-10f);
                float rden = 1.0f / den;
                size_t gbase = (size_t)(b * L_ + l0 + row) * HID_ + h * DH_;
                #pragma unroll
                for (int nt = 0; nt < 4; ++nt)
                    ATT[gbase + nt*16 + lr] = f2b(acc[mt][nt][p] * rden);
            }
        }
    }
}

// ---------------------------------------------------------------------------
extern "C" void kernel_launch(void* const* d_in, const int* in_sizes, int n_in,
                              void* d_out, int out_size, void* d_ws, size_t ws_size,
                              hipStream_t stream)
{
    const float* Xq = (const float*)d_in[0];
    const float* Xs = (const float*)d_in[1];
    const float* Wq = (const float*)d_in[2];
    const float* Wk = (const float*)d_in[3];
    const float* Wv = (const float*)d_in[4];
    const float* Wo = (const float*)d_in[5];
    const float* Pj = (const float*)d_in[6];
    float* out = (float*)d_out;

    // Workspace layout (MB-aligned, audited disjoint per stage / safe alias):
    //   WqT..WoT [0,8)  Xqb [8,40)  Xsb [40,72)  QPb [72,136)
    //   KPb [136,200)   Vb [200,232)
    //   KPt  [8,72)    alias Xqb+Xsb  (dead after gemms)
    //   Vt   [136,168) alias KPb-lo   (KPb dead after kptrans)
    //   KVSP [168,184) alias KPb-mid
    //   KVSt [184,186) alias KPb-hi
    //   ksp  [0,1)     alias WqT      (dead after Q-gemm)
    //   ATT  [200,232) alias Vb       (dead after vtrans)
    char* ws = (char*)d_ws;
    ushort* WqT = (ushort*)(ws + 0);
    ushort* WkT = (ushort*)(ws + 2097152);
    ushort* WvT = (ushort*)(ws + 4194304);
    ushort* WoT = (ushort*)(ws + 6291456);
    ushort* Xqb = (ushort*)(ws + 8388608);
    ushort* Xsb = (ushort*)(ws + 41943040);
    ushort* QPb = (ushort*)(ws + 75497472);
    ushort* KPb = (ushort*)(ws + 142606336);
    ushort* Vb  = (ushort*)(ws + 209715200);
    ushort* KPt = (ushort*)(ws + 8388608);        // 64MB
    ushort* Vt  = (ushort*)(ws + 142606336);      // 32MB
    float*  KVSP = (float*)(ws + 176160768);      // 16MB
    ushort* KVSt = (ushort*)(ws + 192937984);     // 2MB
    float*  ksp  = (float*)(ws + 0);              // 1MB
    ushort* ATT  = Vb;

    dim3 tb(256);

    cvt_bf16<<<4096, tb, 0, stream>>>(Xq, Xqb, BL_*HID_/4);
    cvt_bf16<<<4096, tb, 0, stream>>>(Xs, Xsb, BL_*HID_/4);
    wtrans<<<dim3(16,16), tb, 0, stream>>>(Wq, WqT);
    wtrans<<<dim3(16,16), tb, 0, stream>>>(Wk, WkT);
    wtrans<<<dim3(16,16), tb, 0, stream>>>(Wv, WvT);
    wtrans<<<dim3(16,16), tb, 0, stream>>>(Wo, WoT);

    gemm_phi_mfma<<<dim3(8, 128), tb, 0, stream>>>(Xqb, WqT, Pj, QPb);
    gemm_phi_mfma<<<dim3(8, 128), tb, 0, stream>>>(Xsb, WkT, Pj, KPb);
    gemm_mfma_bf16<<<dim3(8, 128), tb, 0, stream>>>(Xsb, WvT, Vb);

    kptrans_kernel<<<dim3(64, 32), tb, 0, stream>>>(KPb, KPt, ksp);
    vtrans_kernel<<<dim3(64, 32), tb, 0, stream>>>(Vb, Vt);

    kvs_mfma<<<dim3(64, 8), tb, 0, stream>>>(Vt, KPt, KVSP);
    kvs_reduce_kernel<<<64, tb, 0, stream>>>(KVSP, ksp, KVSt);

    numden_mfma<<<dim3(B_*H_, L_/128), tb, 0, stream>>>(QPb, KVSt, ATT);

    gemm_mfma_f32<<<dim3(8, 128), tb, 0, stream>>>(ATT, WoT, out);
    (void)in_sizes; (void)n_in; (void)out_size; (void)ws_size;
}